// Round 6
// baseline (356.546 us; speedup 1.0000x reference)
//
#include <hip/hip_runtime.h>
#include <hip/hip_cooperative_groups.h>

namespace cg = cooperative_groups;

typedef short short8 __attribute__((ext_vector_type(8)));
typedef short short4v __attribute__((ext_vector_type(4)));
typedef float float4v __attribute__((ext_vector_type(4)));
typedef unsigned short ushort_t;
typedef _Float16 half_t;

#define INV_EXT (1.0f / 0.048f)
#define HN 32
#define KK 15
#define CIN 64
#define COUT 64
#define PB 16      /* points per tile */
#define KDIM 1024  /* padded 16 k' * 64 c, order defined by j-map */
#define NSLOT 16   /* stats atomic slots */

__device__ inline ushort_t f32_bf16(float f) {
    unsigned int u = __float_as_uint(f);
    u += 0x7FFFu + ((u >> 16) & 1u);   // round-to-nearest-even
    return (ushort_t)(u >> 16);
}

// wtS element index: row p, logical kd-slot j (0..1023). 16B granule (8 elems)
// XOR-swizzled by p so phase-3 reads (p = lane&15) spread across banks.
__device__ inline int wtJ(int p, int j) {
    return p * KDIM + ((((j >> 3) ^ (p & 7)) << 3) | (j & 7));
}

// ============ single fused cooperative kernel: prep | KPConv | norm ============
template <bool XB>
__global__ __launch_bounds__(256, 4)
void kpconv_fused(const float* __restrict__ q_pts,
                  const float* __restrict__ s_pts,
                  const int*   __restrict__ inds,
                  const float* __restrict__ x,
                  const float* __restrict__ kpts,
                  const float* __restrict__ W,
                  float* __restrict__ out,
                  float* __restrict__ sums,   // ws: NSLOT*128 floats
                  int*   __restrict__ ctr,    // ws: tile-steal counter
                  ushort_t* __restrict__ W3,  // ws: [128 kd-octets][64 d][8] bf16
                  ushort_t* __restrict__ xb,  // ws: [N][64] bf16 channel-permuted
                  int N)
{
    // LDS budget: 3K + 2K + 32K + ~0.5K = ~37.9 KB -> 4 blocks/CU
    __shared__ half_t nXh[PB * HN], nYh[PB * HN], nZh[PB * HN]; // 3 KB (fp16 diffs)
    __shared__ int indS[PB * HN];                               // 2 KB
    __shared__ __align__(16) short wtS[PB * KDIM];              // 32 KB
    __shared__ int tileNextS;
    __shared__ float meanS[64], invS[64];

    cg::grid_group grid = cg::this_grid();
    const int t = threadIdx.x;
    const int gt = blockIdx.x * 256 + t;
    const int gstride = gridDim.x * 256;

    // ================= phase A: prep =================
    for (int i = gt; i < NSLOT * 128; i += gstride) sums[i] = 0.f;
    if (gt == 0) *ctr = gridDim.x;
    for (int i = gt; i < COUT * KDIM; i += gstride) {
        int d = (i >> 3) & 63;
        int j = ((i >> 9) << 3) | (i & 7);         // kd-slot
        int quad = j >> 2, r = j & 3;
        int l15q = quad & 15, e = (quad >> 4) & 3, ct = quad >> 6;
        int k = (e ^ ct) * 4 + r, c = ct * 16 + l15q;
        W3[i] = (k < KK) ? f32_bf16(W[(k * CIN + c) * COUT + d]) : (ushort_t)0;
    }
    if constexpr (XB) {
        // xb[n][tt*4+ct] = bf16(x[n][ct*16+tt]); read AND write coalesced
        int nq = N * 16;
        for (int iq = gt; iq < nq; iq += gstride) {
            int n = iq >> 4, tt = iq & 15;
            const float* xp = x + (size_t)n * 64;
            short4v v;
            v[0] = (short)f32_bf16(xp[tt]);
            v[1] = (short)f32_bf16(xp[tt + 16]);
            v[2] = (short)f32_bf16(xp[tt + 32]);
            v[3] = (short)f32_bf16(xp[tt + 48]);
            *(short4v*)(xb + (size_t)n * 64 + tt * 4) = v;
        }
    }
    grid.sync();

    // ================= phase B: persistent KPConv with tile stealing =========
    const int tiles = (N + PB - 1) / PB;
    const int lane = t & 63;
    const int wid = t >> 6;
    const int l15 = lane & 15;
    const int q = lane >> 4;
    const int d0 = wid * 16;
    const int slot = blockIdx.x & (NSLOT - 1);

    int kidx = l15 < KK ? l15 : 0;
    float kx = kpts[kidx * 3 + 0];
    float ky = kpts[kidx * 3 + 1];
    float kz = kpts[kidx * 3 + 2];
    if (l15 >= KK) { kx = 3e4f; ky = 3e4f; kz = 3e4f; }  // pad k' -> w==0
    const ushort_t* wb = W3 + (size_t)q * 512 + (d0 + l15) * 8;

    int tile = blockIdx.x;
    while (tile < tiles) {
        const int n0 = tile * PB;

        // ---- phase 0: neighbor diffs (fp16) + indices ----
        for (int it = 0; it < 2; ++it) {
            int pi = t + it * 256;          // (p,h)
            int p = pi >> 5, h = pi & 31;
            int n = n0 + p;
            float dx = 1e9f, dy = 1e9f, dz = 1e9f; int idx = 0;
            if (n < N) {
                idx = inds[n * HN + h];
                dx = s_pts[idx * 3 + 0] - q_pts[n * 3 + 0];
                dy = s_pts[idx * 3 + 1] - q_pts[n * 3 + 1];
                dz = s_pts[idx * 3 + 2] - q_pts[n * 3 + 2];
            }
            indS[pi] = idx;
            nXh[pi] = (half_t)dx; nYh[pi] = (half_t)dy; nZh[pi] = (half_t)dz;
        }
        if (t == 0) tileNextS = atomicAdd(ctr, 1);
        __syncthreads();                     // B1: also covers prev-iter wtS readers
        int nextTile = tileNextS;

        // ---- phase 1: influence weights -> A-fragments ----
        short8 afrag[4];
#pragma unroll
        for (int i = 0; i < 4; ++i) {
            int p = wid * 4 + i;
            int base = p * HN + q * 8;
#pragma unroll
            for (int j = 0; j < 8; ++j) {
                float dx = (float)nXh[base + j] - kx;
                float dy = (float)nYh[base + j] - ky;
                float dz = (float)nZh[base + j] - kz;
                float d = __builtin_amdgcn_sqrtf(fmaf(dx, dx, fmaf(dy, dy, dz * dz)));
                float w = fmaxf(fmaf(d, -INV_EXT, 1.0f), 0.0f);
                afrag[i][j] = (short)f32_bf16(w);
            }
        }

        // ---- phase 2: per wave, 4 points: wt[k'][c] = w^T @ feat via MFMA ----
        for (int i = 0; i < 4; ++i) {
            int p = wid * 4 + i;
            short4v L[8];
            const float* rpf[8];
            if constexpr (XB) {
#pragma unroll
                for (int j = 0; j < 8; ++j) {
                    int idx = indS[p * HN + q * 8 + j];
                    L[j] = *(const short4v*)(xb + (size_t)idx * CIN + l15 * 4);
                }
            } else {
#pragma unroll
                for (int j = 0; j < 8; ++j)
                    rpf[j] = x + (size_t)indS[p * HN + q * 8 + j] * CIN;
            }
#pragma unroll
            for (int ct = 0; ct < 4; ++ct) {
                short8 b;
#pragma unroll
                for (int j = 0; j < 8; ++j) {
                    if constexpr (XB) b[j] = L[j][ct];
                    else              b[j] = (short)f32_bf16(rpf[j][ct * 16 + l15]);
                }
                float4v acc = {0.f, 0.f, 0.f, 0.f};
                acc = __builtin_amdgcn_mfma_f32_16x16x32_bf16(afrag[i], b, acc, 0, 0, 0);
                short4v v;
#pragma unroll
                for (int r = 0; r < 4; ++r) v[r] = (short)f32_bf16(acc[r]);
                int quad = l15 + 16 * (q ^ ct) + 64 * ct;
                *(short4v*)&wtS[wtJ(p, quad * 4)] = v;
            }
        }
        __syncthreads();                     // B2

        // ---- phase 3: OUT[16p x 64d] = wt @ W3, + fused stats ----
        {
            float4v acc = {0.f, 0.f, 0.f, 0.f};
#pragma unroll 4
            for (int s = 0; s < 32; ++s) {
                short8 a = *(short8*)&wtS[wtJ(l15, s * 32 + q * 8)];
                short8 b = *(const short8*)(wb + (size_t)s * 2048);
                acc = __builtin_amdgcn_mfma_f32_16x16x32_bf16(a, b, acc, 0, 0, 0);
            }
            float s1 = 0.f, s2 = 0.f;
#pragma unroll
            for (int r = 0; r < 4; ++r) {
                int p = q * 4 + r;
                int n = n0 + p;
                float v = acc[r];
                if (n < N) { out[n * COUT + d0 + l15] = v; s1 += v; s2 += v * v; }
            }
            s1 += __shfl_xor(s1, 16); s2 += __shfl_xor(s2, 16);
            s1 += __shfl_xor(s1, 32); s2 += __shfl_xor(s2, 32);
            if (q == 0) {
                atomicAdd(&sums[slot * 128 + d0 + l15], s1);
                atomicAdd(&sums[slot * 128 + 64 + d0 + l15], s2);
            }
        }
        tile = nextTile;
    }

    grid.sync();

    // ================= phase C: instance-norm + LeakyReLU =================
    if (t < 64) {
        float s1 = 0.f, s2 = 0.f;
#pragma unroll
        for (int sl = 0; sl < NSLOT; ++sl) {
            s1 += sums[sl * 128 + t];
            s2 += sums[sl * 128 + 64 + t];
        }
        float invN = 1.0f / (float)N;
        float mean = s1 * invN;
        float var = fmaxf(s2 * invN - mean * mean, 0.f);
        meanS[t] = mean;
        invS[t] = rsqrtf(var + 1e-5f);
    }
    __syncthreads();
    {
        int total = N * 16;   // float4 groups
        for (int i = gt; i < total; i += gstride) {
            int cb = (i * 4) & 63;
            float4v v = *(float4v*)&out[(size_t)i * 4];
#pragma unroll
            for (int j = 0; j < 4; ++j) {
                float val = (v[j] - meanS[cb + j]) * invS[cb + j];
                v[j] = val >= 0.f ? val : 0.1f * val;
            }
            *(float4v*)&out[(size_t)i * 4] = v;
        }
    }
}

extern "C" void kernel_launch(void* const* d_in, const int* in_sizes, int n_in,
                              void* d_out, int out_size, void* d_ws, size_t ws_size,
                              hipStream_t stream)
{
    const float* q  = (const float*)d_in[0];
    const float* s  = (const float*)d_in[1];
    const int* inds = (const int*)d_in[2];
    const float* x  = (const float*)d_in[3];
    const float* kp = (const float*)d_in[4];
    const float* W  = (const float*)d_in[5];
    float* out = (float*)d_out;
    int N = in_sizes[0] / 3;

    float* sums  = (float*)d_ws;                                 // 8 KB
    int*   ctr   = (int*)((char*)d_ws + 8192);
    ushort_t* W3 = (ushort_t*)((char*)d_ws + 12288);             // 128 KB
    ushort_t* xb = (ushort_t*)((char*)d_ws + 12288 + 131072);
    bool useXB = ws_size >= 12288 + 131072 + (size_t)N * CIN * 2;

    int maxb = 0;
    if (useXB)
        hipOccupancyMaxActiveBlocksPerMultiprocessor(&maxb, (const void*)kpconv_fused<true>, 256, 0);
    else
        hipOccupancyMaxActiveBlocksPerMultiprocessor(&maxb, (const void*)kpconv_fused<false>, 256, 0);
    if (maxb < 1) maxb = 1;
    int grid = maxb * 256;
    if (grid > 1024) grid = 1024;

    void* args[] = {(void*)&q, (void*)&s, (void*)&inds, (void*)&x, (void*)&kp,
                    (void*)&W, (void*)&out, (void*)&sums, (void*)&ctr,
                    (void*)&W3, (void*)&xb, (void*)&N};
    if (useXB)
        hipLaunchCooperativeKernel((const void*)kpconv_fused<true>,
                                   dim3(grid), dim3(256), args, 0, stream);
    else
        hipLaunchCooperativeKernel((const void*)kpconv_fused<false>,
                                   dim3(grid), dim3(256), args, 0, stream);
}

// Round 7
// 330.003 us; speedup vs baseline: 1.0804x; 1.0804x over previous
//
#include <hip/hip_runtime.h>
#include <hip/hip_cooperative_groups.h>

namespace cg = cooperative_groups;

typedef short short8 __attribute__((ext_vector_type(8)));
typedef short short4v __attribute__((ext_vector_type(4)));
typedef float float4v __attribute__((ext_vector_type(4)));
typedef unsigned short ushort_t;

#define INV_EXT (1.0f / 0.048f)
#define HN 32
#define KK 15
#define CIN 64
#define COUT 64
#define PB 16      /* points per tile */
#define KDIM 1024  /* padded 16 k' * 64 c, order defined by j-map */
#define NSLOT 16   /* stats atomic slots */

__device__ inline ushort_t f32_bf16(float f) {
    unsigned int u = __float_as_uint(f);
    u += 0x7FFFu + ((u >> 16) & 1u);   // round-to-nearest-even
    return (ushort_t)(u >> 16);
}

// wtS element index: row p, logical kd-slot j (0..1023). 16B granule (8 elems)
// XOR-swizzled by p so phase-3 reads (p = lane&15) spread across banks.
__device__ inline int wtJ(int p, int j) {
    return p * KDIM + ((((j >> 3) ^ (p & 7)) << 3) | (j & 7));
}

// ============ single fused cooperative kernel: prep | KPConv | norm ============
// Phase B is byte-for-byte the R5 (95.6 us) structure: static tile striding,
// fp32 nbr arrays, no per-tile atomics. LDS exactly 40960 -> 4 blocks/CU.
template <bool XB>
__global__ __launch_bounds__(256, 4)
void kpconv_fused(const float* __restrict__ q_pts,
                  const float* __restrict__ s_pts,
                  const int*   __restrict__ inds,
                  const float* __restrict__ x,
                  const float* __restrict__ kpts,
                  const float* __restrict__ W,
                  float* __restrict__ out,
                  float* __restrict__ sums,   // ws: NSLOT*128 floats
                  ushort_t* __restrict__ W3,  // ws: [128 kd-octets][64 d][8] bf16
                  ushort_t* __restrict__ xb,  // ws: [N][64] bf16 channel-permuted
                  int N)
{
    // exactly 40 KB: 6K nbr + 2K indS + 32K wtS. meanS/invS reuse nX/nY in phase C.
    __shared__ float nX[PB * HN], nY[PB * HN], nZ[PB * HN]; // 6 KB
    __shared__ int indS[PB * HN];                           // 2 KB
    __shared__ __align__(16) short wtS[PB * KDIM];          // 32 KB

    cg::grid_group grid = cg::this_grid();
    const int t = threadIdx.x;
    const int gt = blockIdx.x * 256 + t;
    const int gstride = gridDim.x * 256;

    // ================= phase A: prep =================
    for (int i = gt; i < NSLOT * 128; i += gstride) sums[i] = 0.f;
    for (int i = gt; i < COUT * KDIM; i += gstride) {
        int d = (i >> 3) & 63;
        int j = ((i >> 9) << 3) | (i & 7);         // kd-slot
        int quad = j >> 2, r = j & 3;
        int l15q = quad & 15, e = (quad >> 4) & 3, ct = quad >> 6;
        int k = (e ^ ct) * 4 + r, c = ct * 16 + l15q;
        W3[i] = (k < KK) ? f32_bf16(W[(k * CIN + c) * COUT + d]) : (ushort_t)0;
    }
    if constexpr (XB) {
        // xb[n][tt*4+ct] = bf16(x[n][ct*16+tt]); read AND write coalesced
        int nq = N * 16;
        for (int iq = gt; iq < nq; iq += gstride) {
            int n = iq >> 4, tt = iq & 15;
            const float* xp = x + (size_t)n * 64;
            short4v v;
            v[0] = (short)f32_bf16(xp[tt]);
            v[1] = (short)f32_bf16(xp[tt + 16]);
            v[2] = (short)f32_bf16(xp[tt + 32]);
            v[3] = (short)f32_bf16(xp[tt + 48]);
            *(short4v*)(xb + (size_t)n * 64 + tt * 4) = v;
        }
    }
    grid.sync();

    // ================= phase B: persistent KPConv, static striding ===========
    const int tiles = (N + PB - 1) / PB;
    const int lane = t & 63;
    const int wid = t >> 6;
    const int l15 = lane & 15;
    const int q = lane >> 4;
    const int d0 = wid * 16;
    const int slot = blockIdx.x & (NSLOT - 1);

    int kidx = l15 < KK ? l15 : 0;
    float kx = kpts[kidx * 3 + 0];
    float ky = kpts[kidx * 3 + 1];
    float kz = kpts[kidx * 3 + 2];
    if (l15 >= KK) { kx = 3e4f; ky = 3e4f; kz = 3e4f; }  // pad k' -> w==0
    const ushort_t* wb = W3 + (size_t)q * 512 + (d0 + l15) * 8;

    for (int tile = blockIdx.x; tile < tiles; tile += gridDim.x) {
        const int n0 = tile * PB;

        // ---- phase 0: neighbor diffs + indices ----
        for (int it = 0; it < 2; ++it) {
            int pi = t + it * 256;          // (p,h)
            int p = pi >> 5, h = pi & 31;
            int n = n0 + p;
            float dx = 1e9f, dy = 1e9f, dz = 1e9f; int idx = 0;
            if (n < N) {
                idx = inds[n * HN + h];
                dx = s_pts[idx * 3 + 0] - q_pts[n * 3 + 0];
                dy = s_pts[idx * 3 + 1] - q_pts[n * 3 + 1];
                dz = s_pts[idx * 3 + 2] - q_pts[n * 3 + 2];
            }
            indS[pi] = idx;
            nX[pi] = dx; nY[pi] = dy; nZ[pi] = dz;
        }
        __syncthreads();                     // B1 (also fences prev-iter wtS reads)

        // ---- phase 1: influence weights -> A-fragments ----
        short8 afrag[4];
#pragma unroll
        for (int i = 0; i < 4; ++i) {
            int p = wid * 4 + i;
            int base = p * HN + q * 8;
#pragma unroll
            for (int j = 0; j < 8; ++j) {
                float dx = nX[base + j] - kx;
                float dy = nY[base + j] - ky;
                float dz = nZ[base + j] - kz;
                float d = __builtin_amdgcn_sqrtf(fmaf(dx, dx, fmaf(dy, dy, dz * dz)));
                float w = fmaxf(fmaf(d, -INV_EXT, 1.0f), 0.0f);
                afrag[i][j] = (short)f32_bf16(w);
            }
        }

        // ---- phase 2: per wave, 4 points: wt[k'][c] = w^T @ feat via MFMA ----
        for (int i = 0; i < 4; ++i) {
            int p = wid * 4 + i;
            short4v L[8];
            const float* rpf[8];
            if constexpr (XB) {
#pragma unroll
                for (int j = 0; j < 8; ++j) {
                    int idx = indS[p * HN + q * 8 + j];
                    L[j] = *(const short4v*)(xb + (size_t)idx * CIN + l15 * 4);
                }
            } else {
#pragma unroll
                for (int j = 0; j < 8; ++j)
                    rpf[j] = x + (size_t)indS[p * HN + q * 8 + j] * CIN;
            }
#pragma unroll
            for (int ct = 0; ct < 4; ++ct) {
                short8 b;
#pragma unroll
                for (int j = 0; j < 8; ++j) {
                    if constexpr (XB) b[j] = L[j][ct];
                    else              b[j] = (short)f32_bf16(rpf[j][ct * 16 + l15]);
                }
                float4v acc = {0.f, 0.f, 0.f, 0.f};
                acc = __builtin_amdgcn_mfma_f32_16x16x32_bf16(afrag[i], b, acc, 0, 0, 0);
                short4v v;
#pragma unroll
                for (int r = 0; r < 4; ++r) v[r] = (short)f32_bf16(acc[r]);
                int quad = l15 + 16 * (q ^ ct) + 64 * ct;
                *(short4v*)&wtS[wtJ(p, quad * 4)] = v;
            }
        }
        __syncthreads();                     // B2

        // ---- phase 3: OUT[16p x 64d] = wt @ W3, + fused stats ----
        {
            float4v acc = {0.f, 0.f, 0.f, 0.f};
#pragma unroll 4
            for (int s = 0; s < 32; ++s) {
                short8 a = *(short8*)&wtS[wtJ(l15, s * 32 + q * 8)];
                short8 b = *(const short8*)(wb + (size_t)s * 2048);
                acc = __builtin_amdgcn_mfma_f32_16x16x32_bf16(a, b, acc, 0, 0, 0);
            }
            float s1 = 0.f, s2 = 0.f;
#pragma unroll
            for (int r = 0; r < 4; ++r) {
                int p = q * 4 + r;
                int n = n0 + p;
                float v = acc[r];
                if (n < N) { out[n * COUT + d0 + l15] = v; s1 += v; s2 += v * v; }
            }
            s1 += __shfl_xor(s1, 16); s2 += __shfl_xor(s2, 16);
            s1 += __shfl_xor(s1, 32); s2 += __shfl_xor(s2, 32);
            if (q == 0) {
                atomicAdd(&sums[slot * 128 + d0 + l15], s1);
                atomicAdd(&sums[slot * 128 + 64 + d0 + l15], s2);
            }
        }
    }

    grid.sync();

    // ================= phase C: instance-norm + LeakyReLU =================
    // meanS/invS live in the (dead) nX/nY LDS regions.
    float* meanS = nX;
    float* invS = nY;
    if (t < 64) {
        float s1 = 0.f, s2 = 0.f;
#pragma unroll
        for (int sl = 0; sl < NSLOT; ++sl) {
            s1 += sums[sl * 128 + t];
            s2 += sums[sl * 128 + 64 + t];
        }
        float invN = 1.0f / (float)N;
        float mean = s1 * invN;
        float var = fmaxf(s2 * invN - mean * mean, 0.f);
        meanS[t] = mean;
        invS[t] = rsqrtf(var + 1e-5f);
    }
    __syncthreads();
    {
        int total = N * 16;   // float4 groups
        for (int i = gt; i < total; i += gstride) {
            int cb = (i * 4) & 63;
            float4v v = *(float4v*)&out[(size_t)i * 4];
#pragma unroll
            for (int j = 0; j < 4; ++j) {
                float val = (v[j] - meanS[cb + j]) * invS[cb + j];
                v[j] = val >= 0.f ? val : 0.1f * val;
            }
            *(float4v*)&out[(size_t)i * 4] = v;
        }
    }
}

extern "C" void kernel_launch(void* const* d_in, const int* in_sizes, int n_in,
                              void* d_out, int out_size, void* d_ws, size_t ws_size,
                              hipStream_t stream)
{
    const float* q  = (const float*)d_in[0];
    const float* s  = (const float*)d_in[1];
    const int* inds = (const int*)d_in[2];
    const float* x  = (const float*)d_in[3];
    const float* kp = (const float*)d_in[4];
    const float* W  = (const float*)d_in[5];
    float* out = (float*)d_out;
    int N = in_sizes[0] / 3;

    float* sums  = (float*)d_ws;                                 // 8 KB
    ushort_t* W3 = (ushort_t*)((char*)d_ws + 8192);              // 128 KB
    ushort_t* xb = (ushort_t*)((char*)d_ws + 8192 + 131072);
    bool useXB = ws_size >= 8192 + 131072 + (size_t)N * CIN * 2;

    int maxb = 0;
    if (useXB)
        hipOccupancyMaxActiveBlocksPerMultiprocessor(&maxb, (const void*)kpconv_fused<true>, 256, 0);
    else
        hipOccupancyMaxActiveBlocksPerMultiprocessor(&maxb, (const void*)kpconv_fused<false>, 256, 0);
    if (maxb < 1) maxb = 1;
    int grid = maxb * 256;
    if (grid > 1024) grid = 1024;

    void* args[] = {(void*)&q, (void*)&s, (void*)&inds, (void*)&x, (void*)&kp,
                    (void*)&W, (void*)&out, (void*)&sums,
                    (void*)&W3, (void*)&xb, (void*)&N};
    if (useXB)
        hipLaunchCooperativeKernel((const void*)kpconv_fused<true>,
                                   dim3(grid), dim3(256), args, 0, stream);
    else
        hipLaunchCooperativeKernel((const void*)kpconv_fused<false>,
                                   dim3(grid), dim3(256), args, 0, stream);
}

// Round 8
// 187.405 us; speedup vs baseline: 1.9025x; 1.7609x over previous
//
#include <hip/hip_runtime.h>

typedef short short8 __attribute__((ext_vector_type(8)));
typedef short short4v __attribute__((ext_vector_type(4)));
typedef float float4v __attribute__((ext_vector_type(4)));
typedef unsigned short ushort_t;

#define INV_EXT (1.0f / 0.048f)
#define HN 32
#define KK 15
#define CIN 64
#define COUT 64
#define PB 16      /* points per block */
#define KDIM 1024  /* padded 16 k' * 64 c, order defined by j-map */
#define NSLOT 16   /* stats atomic slots */

__device__ inline ushort_t f32_bf16(float f) {
    unsigned int u = __float_as_uint(f);
    u += 0x7FFFu + ((u >> 16) & 1u);   // round-to-nearest-even
    return (ushort_t)(u >> 16);
}

// wtS element index: row p, logical kd-slot j (0..1023). 16B granule (8 elems)
// XOR-swizzled by p so phase-3 reads (p = lane&15) spread across banks.
__device__ inline int wtJ(int p, int j) {
    return p * KDIM + ((((j >> 3) ^ (p & 7)) << 3) | (j & 7));
}

// ================= K1: main KPConv (fused slotted stats) =================
template <bool XB>
__global__ __launch_bounds__(256, 4)
void kpconv_main(const float* __restrict__ q_pts,
                 const float* __restrict__ s_pts,
                 const int*   __restrict__ inds,
                 const float* __restrict__ x,
                 const float* __restrict__ kpts,
                 const ushort_t* __restrict__ W3,   // [128 kd-octets][64 d][8] bf16
                 const ushort_t* __restrict__ xb,   // [N][64] bf16, channel-permuted
                 float* __restrict__ out,
                 float* __restrict__ sums, int N)
{
    __shared__ float nX[PB * HN], nY[PB * HN], nZ[PB * HN]; // 6 KB
    __shared__ int indS[PB * HN];                           // 2 KB
    __shared__ __align__(16) short wtS[PB * KDIM];          // 32 KB

    const int t = threadIdx.x;
    const int n0 = blockIdx.x * PB;
    const int lane = t & 63;
    const int wid = t >> 6;
    const int l15 = lane & 15;
    const int q = lane >> 4;

    // ---- pre-step: neighbor diffs + indices (block-wide) ----
    for (int it = 0; it < 2; ++it) {
        int pi = t + it * 256;          // (p,h)
        int p = pi >> 5, h = pi & 31;
        int n = n0 + p;
        float dx = 1e9f, dy = 1e9f, dz = 1e9f; int idx = 0;
        if (n < N) {
            idx = inds[n * HN + h];
            dx = s_pts[idx * 3 + 0] - q_pts[n * 3 + 0];
            dy = s_pts[idx * 3 + 1] - q_pts[n * 3 + 1];
            dz = s_pts[idx * 3 + 2] - q_pts[n * 3 + 2];
        }
        indS[pi] = idx;
        nX[pi] = dx; nY[pi] = dy; nZ[pi] = dz;
    }
    __syncthreads();

    // ---- phase 1: influence weights straight into A-fragment registers ----
    // A-frag (16x16x32): lane holds A[m=k'=l15][k=h=q*8+j] = w[h][k']
    int kidx = l15 < KK ? l15 : 0;
    float kx = kpts[kidx * 3 + 0];
    float ky = kpts[kidx * 3 + 1];
    float kz = kpts[kidx * 3 + 2];
    // pad kernel point (l15 >= KK): push it 3e4 away -> w clamps to 0.
    if (l15 >= KK) { kx = 3e4f; ky = 3e4f; kz = 3e4f; }
    short8 afrag[4];
#pragma unroll
    for (int i = 0; i < 4; ++i) {
        int p = wid * 4 + i;
        int base = p * HN + q * 8;       // 16B-aligned: byte addr 128p+32q
        float4v x0 = *(float4v*)&nX[base], x1 = *(float4v*)&nX[base + 4];
        float4v y0 = *(float4v*)&nY[base], y1 = *(float4v*)&nY[base + 4];
        float4v z0 = *(float4v*)&nZ[base], z1 = *(float4v*)&nZ[base + 4];
#pragma unroll
        for (int j = 0; j < 8; ++j) {
            float dx = (j < 4 ? x0[j & 3] : x1[j & 3]) - kx;
            float dy = (j < 4 ? y0[j & 3] : y1[j & 3]) - ky;
            float dz = (j < 4 ? z0[j & 3] : z1[j & 3]) - kz;
            float d = __builtin_amdgcn_sqrtf(fmaf(dx, dx, fmaf(dy, dy, dz * dz)));
            float w = fmaxf(fmaf(d, -INV_EXT, 1.0f), 0.0f);
            afrag[i][j] = (short)f32_bf16(w);
        }
    }

    // ---- phase 2: per wave, 4 points: wt[k'][c] = w^T @ feat via MFMA ----
    // Hoist ALL 32 gathers (4 points x 8 rows) before any compute: 4x the
    // outstanding loads per wave (LDS binds occupancy, VGPRs are free).
    short4v L[4][8];
    if constexpr (XB) {
#pragma unroll
        for (int i = 0; i < 4; ++i)
#pragma unroll
            for (int j = 0; j < 8; ++j) {
                int idx = indS[(wid * 4 + i) * HN + q * 8 + j];
                L[i][j] = *(const short4v*)(xb + (size_t)idx * CIN + l15 * 4);
            }
    }
#pragma unroll
    for (int i = 0; i < 4; ++i) {
        int p = wid * 4 + i;
        const float* rpf[8];
        if constexpr (!XB) {
#pragma unroll
            for (int j = 0; j < 8; ++j)
                rpf[j] = x + (size_t)indS[p * HN + q * 8 + j] * CIN;
        }
#pragma unroll
        for (int ct = 0; ct < 4; ++ct) {
            short8 b;
#pragma unroll
            for (int j = 0; j < 8; ++j) {
                if constexpr (XB) b[j] = L[i][j][ct];
                else              b[j] = (short)f32_bf16(rpf[j][ct * 16 + l15]);
            }
            float4v acc = {0.f, 0.f, 0.f, 0.f};
            acc = __builtin_amdgcn_mfma_f32_16x16x32_bf16(afrag[i], b, acc, 0, 0, 0);
            // D row m = k' = q*4+r, col n = c = ct*16+l15.
            // kd-slot j(k',c) = quad*4 + r, quad = l15 + 16*(q^ct) + 64*ct
            short4v v;
#pragma unroll
            for (int r = 0; r < 4; ++r) v[r] = (short)f32_bf16(acc[r]);
            int quad = l15 + 16 * (q ^ ct) + 64 * ct;
            *(short4v*)&wtS[wtJ(p, quad * 4)] = v;
        }
    }
    __syncthreads();

    // ---- phase 3: OUT[16p x 64d] = wt[16p x 1024j] @ W3[1024j x 64d] ----
    {
        const int d0 = wid * 16;
        float4v acc = {0.f, 0.f, 0.f, 0.f};
        // B-frag: lane needs W3 j-slots s*32+q*8+(0..7) at col d0+l15 ->
        // octet (s*4+q), contiguous 16B: fully coalesced dwordx4
        const ushort_t* wb = W3 + (size_t)q * 512 + (d0 + l15) * 8;
#pragma unroll 4
        for (int s = 0; s < 32; ++s) {
            short8 a = *(short8*)&wtS[wtJ(l15, s * 32 + q * 8)];
            short8 b = *(const short8*)(wb + (size_t)s * 2048);
            acc = __builtin_amdgcn_mfma_f32_16x16x32_bf16(a, b, acc, 0, 0, 0);
        }
        // store + fused per-channel stats (slotted atomics)
        float s1 = 0.f, s2 = 0.f;
#pragma unroll
        for (int r = 0; r < 4; ++r) {
            int p = q * 4 + r;
            int n = n0 + p;
            float v = acc[r];
            if (n < N) { out[n * COUT + d0 + l15] = v; s1 += v; s2 += v * v; }
        }
        s1 += __shfl_xor(s1, 16); s2 += __shfl_xor(s2, 16);
        s1 += __shfl_xor(s1, 32); s2 += __shfl_xor(s2, 32);
        if (q == 0) {
            int slot = blockIdx.x & (NSLOT - 1);
            atomicAdd(&sums[slot * 128 + d0 + l15], s1);
            atomicAdd(&sums[slot * 128 + 64 + d0 + l15], s2);
        }
    }
}

// ================= K0: prep (zero stats, W->W3 blocked layout, x->xb permuted) ===
template <bool XB>
__global__ void prep_kernel(const float* __restrict__ W, const float* __restrict__ x,
                            float* sums, ushort_t* W3, ushort_t* xb, int N)
{
    long gt = (long)blockIdx.x * 256 + threadIdx.x;
    long stride = (long)gridDim.x * 256;
    if (gt < NSLOT * 128) sums[gt] = 0.f;
    for (long i = gt; i < COUT * KDIM; i += stride) {
        int d = (int)((i >> 3) & 63);
        int j = (int)(((i >> 9) << 3) | (i & 7));  // kd-slot
        int quad = j >> 2, r = j & 3;
        int l15 = quad & 15, e = (quad >> 4) & 3, ct = quad >> 6;
        int k = (e ^ ct) * 4 + r, c = ct * 16 + l15;
        W3[i] = (k < KK) ? f32_bf16(W[(k * CIN + c) * COUT + d]) : (ushort_t)0;
    }
    if constexpr (XB) {
        // xb[n][tt*4+ct] = bf16(x[n][ct*16+tt]); read AND write coalesced
        long nq = (long)N * 16;
        for (long iq = gt; iq < nq; iq += stride) {
            long n = iq >> 4; int tt = (int)(iq & 15);
            const float* xp = x + n * 64;
            short4v v;
            v[0] = (short)f32_bf16(xp[tt]);
            v[1] = (short)f32_bf16(xp[tt + 16]);
            v[2] = (short)f32_bf16(xp[tt + 32]);
            v[3] = (short)f32_bf16(xp[tt + 48]);
            *(short4v*)(xb + n * 64 + tt * 4) = v;
        }
    }
}

// ================= K2: reduce slots + instance-norm + LeakyReLU ========
__global__ void norm_kernel(float* out, const float* __restrict__ sums, int N)
{
    __shared__ float meanS[64], invS[64];
    int t = threadIdx.x;
    if (t < 64) {
        float s1 = 0.f, s2 = 0.f;
#pragma unroll
        for (int sl = 0; sl < NSLOT; ++sl) {
            s1 += sums[sl * 128 + t];
            s2 += sums[sl * 128 + 64 + t];
        }
        float invN = 1.0f / (float)N;
        float mean = s1 * invN;
        float var = fmaxf(s2 * invN - mean * mean, 0.f);
        meanS[t] = mean;
        invS[t] = rsqrtf(var + 1e-5f);
    }
    __syncthreads();
    long total = (long)N * 64 / 4;
    for (long i = (long)blockIdx.x * blockDim.x + t; i < total;
         i += (long)gridDim.x * blockDim.x) {
        int cb = (int)((i * 4) & 63);
        float4v v = *(float4v*)&out[i * 4];
#pragma unroll
        for (int j = 0; j < 4; ++j) {
            float val = (v[j] - meanS[cb + j]) * invS[cb + j];
            v[j] = val >= 0.f ? val : 0.1f * val;
        }
        *(float4v*)&out[i * 4] = v;
    }
}

extern "C" void kernel_launch(void* const* d_in, const int* in_sizes, int n_in,
                              void* d_out, int out_size, void* d_ws, size_t ws_size,
                              hipStream_t stream)
{
    const float* q  = (const float*)d_in[0];
    const float* s  = (const float*)d_in[1];
    const int* inds = (const int*)d_in[2];
    const float* x  = (const float*)d_in[3];
    const float* kp = (const float*)d_in[4];
    const float* W  = (const float*)d_in[5];
    float* out = (float*)d_out;
    int N = in_sizes[0] / 3;

    float* sums  = (float*)d_ws;                                // 8 KB
    ushort_t* W3 = (ushort_t*)((char*)d_ws + 8192);             // 128 KB
    ushort_t* xb = (ushort_t*)((char*)d_ws + 8192 + 131072);
    bool useXB = ws_size >= 8192 + 131072 + (size_t)N * CIN * 2;

    int nblk = (N + PB - 1) / PB;
    if (useXB) {
        prep_kernel<true ><<<512, 256, 0, stream>>>(W, x, sums, W3, xb, N);
        kpconv_main<true ><<<nblk, 256, 0, stream>>>(q, s, inds, x, kp, W3, xb, out, sums, N);
    } else {
        prep_kernel<false><<<512, 256, 0, stream>>>(W, x, sums, W3, xb, N);
        kpconv_main<false><<<nblk, 256, 0, stream>>>(q, s, inds, x, kp, W3, xb, out, sums, N);
    }
    norm_kernel<<<1024, 256, 0, stream>>>(out, sums, N);
}

// Round 9
// 183.787 us; speedup vs baseline: 1.9400x; 1.0197x over previous
//
#include <hip/hip_runtime.h>

typedef short short8 __attribute__((ext_vector_type(8)));
typedef short short4v __attribute__((ext_vector_type(4)));
typedef float float4v __attribute__((ext_vector_type(4)));
typedef unsigned int uint2v __attribute__((ext_vector_type(2)));
typedef unsigned int uint4v __attribute__((ext_vector_type(4)));
typedef unsigned short ushort_t;

#define INV_EXT (1.0f / 0.048f)
#define HN 32
#define KK 15
#define CIN 64
#define COUT 64
#define PB 16      /* points per block */
#define KDIM 1024  /* padded 16 k' * 64 c, order defined by j-map */
#define NSLOT 16   /* stats atomic slots */

// round-half-up bf16 (max rel err identical to RNE; no tie logic -> 1 add)
__device__ inline ushort_t rh_bf16(float f) {
    return (ushort_t)((__float_as_uint(f) + 0x8000u) >> 16);
}
// pack two floats into two bf16 in one u32 (lo = a, hi = b)
__device__ inline unsigned pk_bf16(float a, float b) {
    unsigned ua = __float_as_uint(a) + 0x8000u;
    unsigned ub = __float_as_uint(b) + 0x8000u;
    return (ua >> 16) | (ub & 0xffff0000u);
}

union Frag8 { short8 s; uint4v u; };

// wtS element index: row p, logical kd-slot j (0..1023). 16B granule (8 elems)
// XOR-swizzled by p so phase-3 reads (p = lane&15) spread across banks.
__device__ inline int wtJ(int p, int j) {
    return p * KDIM + ((((j >> 3) ^ (p & 7)) << 3) | (j & 7));
}

// ================= K1: main KPConv (fused slotted stats) =================
template <bool XB>
__global__ __launch_bounds__(256, 4)
void kpconv_main(const float* __restrict__ q_pts,
                 const float* __restrict__ s_pts,
                 const int*   __restrict__ inds,
                 const float* __restrict__ x,
                 const float* __restrict__ kpts,
                 const ushort_t* __restrict__ W3,   // [128 kd-octets][64 d][8] bf16
                 const ushort_t* __restrict__ xb,   // [N][64] bf16, channel-permuted
                 float* __restrict__ out,
                 float* __restrict__ sums, int N)
{
    __shared__ float nX[PB * HN], nY[PB * HN], nZ[PB * HN]; // 6 KB
    __shared__ int indS[PB * HN];                           // 2 KB
    __shared__ __align__(16) short wtS[PB * KDIM];          // 32 KB

    const int t = threadIdx.x;
    const int n0 = blockIdx.x * PB;
    const int lane = t & 63;
    const int wid = t >> 6;
    const int l15 = lane & 15;
    const int q = lane >> 4;

    // ---- pre-step: neighbor diffs + indices (block-wide) ----
    for (int it = 0; it < 2; ++it) {
        int pi = t + it * 256;          // (p,h)
        int p = pi >> 5, h = pi & 31;
        int n = n0 + p;
        float dx = 1e9f, dy = 1e9f, dz = 1e9f; int idx = 0;
        if (n < N) {
            idx = inds[n * HN + h];
            dx = s_pts[idx * 3 + 0] - q_pts[n * 3 + 0];
            dy = s_pts[idx * 3 + 1] - q_pts[n * 3 + 1];
            dz = s_pts[idx * 3 + 2] - q_pts[n * 3 + 2];
        }
        indS[pi] = idx;
        nX[pi] = dx; nY[pi] = dy; nZ[pi] = dz;
    }
    __syncthreads();

    // ---- gather ALL phase-2 B rows NOW: latency hides under phase-1 VALU ----
    short4v L[4][8];
    if constexpr (XB) {
#pragma unroll
        for (int i = 0; i < 4; ++i)
#pragma unroll
            for (int j = 0; j < 8; ++j) {
                int idx = indS[(wid * 4 + i) * HN + q * 8 + j];
                L[i][j] = *(const short4v*)(xb + (size_t)idx * CIN + l15 * 4);
            }
    }

    // ---- phase 1: influence weights straight into A-fragment registers ----
    // A-frag (16x16x32): lane holds A[m=k'=l15][k=h=q*8+j] = w[h][k']
    int kidx = l15 < KK ? l15 : 0;
    float kx = kpts[kidx * 3 + 0];
    float ky = kpts[kidx * 3 + 1];
    float kz = kpts[kidx * 3 + 2];
    // pad kernel point (l15 >= KK): push it 3e4 away -> w clamps to 0.
    if (l15 >= KK) { kx = 3e4f; ky = 3e4f; kz = 3e4f; }
    Frag8 afrag[4];
#pragma unroll
    for (int i = 0; i < 4; ++i) {
        int p = wid * 4 + i;
        int base = p * HN + q * 8;       // 16B-aligned
        float4v x0 = *(float4v*)&nX[base], x1 = *(float4v*)&nX[base + 4];
        float4v y0 = *(float4v*)&nY[base], y1 = *(float4v*)&nY[base + 4];
        float4v z0 = *(float4v*)&nZ[base], z1 = *(float4v*)&nZ[base + 4];
        float w[8];
#pragma unroll
        for (int j = 0; j < 8; ++j) {
            float dx = (j < 4 ? x0[j & 3] : x1[j & 3]) - kx;
            float dy = (j < 4 ? y0[j & 3] : y1[j & 3]) - ky;
            float dz = (j < 4 ? z0[j & 3] : z1[j & 3]) - kz;
            float d = __builtin_amdgcn_sqrtf(fmaf(dx, dx, fmaf(dy, dy, dz * dz)));
            w[j] = fmaxf(fmaf(d, -INV_EXT, 1.0f), 0.0f);
        }
#pragma unroll
        for (int jj = 0; jj < 4; ++jj)
            afrag[i].u[jj] = pk_bf16(w[2 * jj], w[2 * jj + 1]);
    }

    // ---- phase 2: per wave, 4 points: wt[k'][c] = w^T @ feat via MFMA ----
#pragma unroll
    for (int i = 0; i < 4; ++i) {
        int p = wid * 4 + i;
        const float* rpf[8];
        if constexpr (!XB) {
#pragma unroll
            for (int j = 0; j < 8; ++j)
                rpf[j] = x + (size_t)indS[p * HN + q * 8 + j] * CIN;
        }
#pragma unroll
        for (int ct = 0; ct < 4; ++ct) {
            short8 b;
#pragma unroll
            for (int j = 0; j < 8; ++j) {
                if constexpr (XB) b[j] = L[i][j][ct];
                else              b[j] = (short)rh_bf16(rpf[j][ct * 16 + l15]);
            }
            float4v acc = {0.f, 0.f, 0.f, 0.f};
            acc = __builtin_amdgcn_mfma_f32_16x16x32_bf16(afrag[i].s, b, acc, 0, 0, 0);
            // D row m = k' = q*4+r, col n = c = ct*16+l15.
            // kd-slot j(k',c) = quad*4 + r, quad = l15 + 16*(q^ct) + 64*ct
            uint2v v2;
            v2[0] = pk_bf16(acc[0], acc[1]);
            v2[1] = pk_bf16(acc[2], acc[3]);
            int quad = l15 + 16 * (q ^ ct) + 64 * ct;
            *(uint2v*)&wtS[wtJ(p, quad * 4)] = v2;
        }
    }
    __syncthreads();

    // ---- phase 3: OUT[16p x 64d] = wt[16p x 1024j] @ W3[1024j x 64d] ----
    {
        const int d0 = wid * 16;
        float4v acc = {0.f, 0.f, 0.f, 0.f};
        // B-frag: lane needs W3 j-slots s*32+q*8+(0..7) at col d0+l15 ->
        // octet (s*4+q), contiguous 16B: fully coalesced dwordx4
        const ushort_t* wb = W3 + (size_t)q * 512 + (d0 + l15) * 8;
#pragma unroll 8
        for (int s = 0; s < 32; ++s) {
            short8 a = *(short8*)&wtS[wtJ(l15, s * 32 + q * 8)];
            short8 b = *(const short8*)(wb + (size_t)s * 2048);
            acc = __builtin_amdgcn_mfma_f32_16x16x32_bf16(a, b, acc, 0, 0, 0);
        }
        // store + fused per-channel stats (slotted atomics)
        float s1 = 0.f, s2 = 0.f;
#pragma unroll
        for (int r = 0; r < 4; ++r) {
            int p = q * 4 + r;
            int n = n0 + p;
            float v = acc[r];
            if (n < N) { out[n * COUT + d0 + l15] = v; s1 += v; s2 += v * v; }
        }
        s1 += __shfl_xor(s1, 16); s2 += __shfl_xor(s2, 16);
        s1 += __shfl_xor(s1, 32); s2 += __shfl_xor(s2, 32);
        if (q == 0) {
            int slot = blockIdx.x & (NSLOT - 1);
            atomicAdd(&sums[slot * 128 + d0 + l15], s1);
            atomicAdd(&sums[slot * 128 + 64 + d0 + l15], s2);
        }
    }
}

// ================= K0: prep (zero stats, W->W3 blocked layout, x->xb permuted) ===
template <bool XB>
__global__ void prep_kernel(const float* __restrict__ W, const float* __restrict__ x,
                            float* sums, ushort_t* W3, ushort_t* xb, int N)
{
    long gt = (long)blockIdx.x * 256 + threadIdx.x;
    long stride = (long)gridDim.x * 256;
    if (gt < NSLOT * 128) sums[gt] = 0.f;
    for (long i = gt; i < COUT * KDIM; i += stride) {
        int d = (int)((i >> 3) & 63);
        int j = (int)(((i >> 9) << 3) | (i & 7));  // kd-slot
        int quad = j >> 2, r = j & 3;
        int l15 = quad & 15, e = (quad >> 4) & 3, ct = quad >> 6;
        int k = (e ^ ct) * 4 + r, c = ct * 16 + l15;
        W3[i] = (k < KK) ? rh_bf16(W[(k * CIN + c) * COUT + d]) : (ushort_t)0;
    }
    if constexpr (XB) {
        // xb[n][tt*4+ct] = bf16(x[n][ct*16+tt]); read AND write coalesced
        long nq = (long)N * 16;
        for (long iq = gt; iq < nq; iq += stride) {
            long n = iq >> 4; int tt = (int)(iq & 15);
            const float* xp = x + n * 64;
            uint2v v;
            v[0] = pk_bf16(xp[tt], xp[tt + 16]);
            v[1] = pk_bf16(xp[tt + 32], xp[tt + 48]);
            *(uint2v*)(xb + n * 64 + tt * 4) = v;
        }
    }
}

// ================= K2: reduce slots + instance-norm + LeakyReLU ========
__global__ void norm_kernel(float* out, const float* __restrict__ sums, int N)
{
    __shared__ float meanS[64], invS[64];
    int t = threadIdx.x;
    if (t < 64) {
        float s1 = 0.f, s2 = 0.f;
#pragma unroll
        for (int sl = 0; sl < NSLOT; ++sl) {
            s1 += sums[sl * 128 + t];
            s2 += sums[sl * 128 + 64 + t];
        }
        float invN = 1.0f / (float)N;
        float mean = s1 * invN;
        float var = fmaxf(s2 * invN - mean * mean, 0.f);
        meanS[t] = mean;
        invS[t] = rsqrtf(var + 1e-5f);
    }
    __syncthreads();
    long total = (long)N * 64 / 4;
    for (long i = (long)blockIdx.x * blockDim.x + t; i < total;
         i += (long)gridDim.x * blockDim.x) {
        int cb = (int)((i * 4) & 63);
        float4v v = *(float4v*)&out[i * 4];
#pragma unroll
        for (int j = 0; j < 4; ++j) {
            float val = (v[j] - meanS[cb + j]) * invS[cb + j];
            v[j] = val >= 0.f ? val : 0.1f * val;
        }
        *(float4v*)&out[i * 4] = v;
    }
}

extern "C" void kernel_launch(void* const* d_in, const int* in_sizes, int n_in,
                              void* d_out, int out_size, void* d_ws, size_t ws_size,
                              hipStream_t stream)
{
    const float* q  = (const float*)d_in[0];
    const float* s  = (const float*)d_in[1];
    const int* inds = (const int*)d_in[2];
    const float* x  = (const float*)d_in[3];
    const float* kp = (const float*)d_in[4];
    const float* W  = (const float*)d_in[5];
    float* out = (float*)d_out;
    int N = in_sizes[0] / 3;

    float* sums  = (float*)d_ws;                                // 8 KB
    ushort_t* W3 = (ushort_t*)((char*)d_ws + 8192);             // 128 KB
    ushort_t* xb = (ushort_t*)((char*)d_ws + 8192 + 131072);
    bool useXB = ws_size >= 8192 + 131072 + (size_t)N * CIN * 2;

    int nblk = (N + PB - 1) / PB;
    if (useXB) {
        prep_kernel<true ><<<512, 256, 0, stream>>>(W, x, sums, W3, xb, N);
        kpconv_main<true ><<<nblk, 256, 0, stream>>>(q, s, inds, x, kp, W3, xb, out, sums, N);
    } else {
        prep_kernel<false><<<512, 256, 0, stream>>>(W, x, sums, W3, xb, N);
        kpconv_main<false><<<nblk, 256, 0, stream>>>(q, s, inds, x, kp, W3, xb, out, sums, N);
    }
    norm_kernel<<<1024, 256, 0, stream>>>(out, sums, N);
}